// Round 1
// baseline (79.251 us; speedup 1.0000x reference)
//
#include <hip/hip_runtime.h>
#include <math.h>

// WildcatPool2d: x[32,64,64,512] fp32 -> out[32,512] fp32
// out[b,c] = mean(top20 over 4096 spatial) + mean(bottom20 over 4096 spatial)

constexpr int CH    = 512;    // channels
constexpr int NROWS = 4096;   // H*W
constexpr int NB    = 8;      // batches of 32 per thread (256 elems/thread)
constexpr int K     = 20;

__device__ __forceinline__ void ce_desc(float& a, float& b) {
  float hi = fmaxf(a, b);
  float lo = fminf(a, b);
  a = hi; b = lo;
}
__device__ __forceinline__ void ce_asc(float& a, float& b) {
  float lo = fminf(a, b);
  float hi = fmaxf(a, b);
  a = lo; b = hi;
}

// full bitonic sort of 32 registers, descending
__device__ __forceinline__ void sort32_desc(float* v) {
  #pragma unroll
  for (int k = 2; k <= 32; k <<= 1) {
    #pragma unroll
    for (int j = k >> 1; j > 0; j >>= 1) {
      #pragma unroll
      for (int i = 0; i < 32; ++i) {
        int l = i ^ j;
        if (l > i) {
          if ((i & k) == 0) ce_desc(v[i], v[l]);
          else              ce_asc(v[i], v[l]);
        }
      }
    }
  }
}

// clean a 32-length bitonic sequence into descending order
__device__ __forceinline__ void clean32_desc(float* v) {
  #pragma unroll
  for (int j = 16; j > 0; j >>= 1) {
    #pragma unroll
    for (int i = 0; i < 32; ++i) {
      int l = i ^ j;
      if (l > i) ce_desc(v[i], v[l]);
    }
  }
}
// clean a 32-length bitonic sequence into ascending order
__device__ __forceinline__ void clean32_asc(float* v) {
  #pragma unroll
  for (int j = 16; j > 0; j >>= 1) {
    #pragma unroll
    for (int i = 0; i < 32; ++i) {
      int l = i ^ j;
      if (l > i) ce_asc(v[i], v[l]);
    }
  }
}

// merge a descending-sorted 32-array d into top (descending, keeps 32 largest)
__device__ __forceinline__ void merge_top(float* top, const float* d) {
  #pragma unroll
  for (int i = 0; i < 32; ++i) top[i] = fmaxf(top[i], d[31 - i]);
  clean32_desc(top);
}
// merge a descending-sorted 32-array d into bot (ascending, keeps 32 smallest)
__device__ __forceinline__ void merge_bot(float* bot, const float* d) {
  #pragma unroll
  for (int i = 0; i < 32; ++i) bot[i] = fminf(bot[i], d[i]);
  clean32_asc(bot);
}

__global__ __launch_bounds__(512)
void wildcat_topk_kernel(const float* __restrict__ x, float* __restrict__ out) {
  const int b     = blockIdx.x >> 4;           // 32 batches
  const int cbase = (blockIdx.x & 15) << 5;    // 16 channel groups of 32
  const int w     = threadIdx.x >> 6;          // wave 0..7
  const int lane  = threadIdx.x & 63;
  const int c     = cbase + (lane & 31);
  const int rpar  = lane >> 5;                 // row parity 0/1

  // wave w owns rows [w*512, w*512+512); lane parity splits even/odd rows
  const float* p0 = x + ((size_t)(b * NROWS + w * 512 + rpar)) * CH + c;

  float top[32], bot[32];
  #pragma unroll
  for (int i = 0; i < 32; ++i) { top[i] = -INFINITY; bot[i] = INFINITY; }

  for (int t = 0; t < NB; ++t) {
    float v[32];
    #pragma unroll
    for (int u = 0; u < 32; ++u)
      v[u] = p0[((size_t)(t * 32 + u)) * (2 * CH)];   // stride 2 rows
    sort32_desc(v);
    merge_top(top, v);
    merge_bot(bot, v);
  }

  // --- intra-wave merge: lane l <-> l+32 (same channel, other row parity) ---
  {
    float pt[32], pb[32];
    #pragma unroll
    for (int i = 0; i < 32; ++i) pt[i] = __shfl_xor(top[i], 32, 64);
    #pragma unroll
    for (int i = 0; i < 32; ++i) pb[i] = __shfl_xor(bot[i], 32, 64);
    // pt descending -> reversed it's ascending; merge formula:
    #pragma unroll
    for (int i = 0; i < 32; ++i) top[i] = fmaxf(top[i], pt[31 - i]);
    clean32_desc(top);
    // pb ascending -> pb[31-i] is descending
    #pragma unroll
    for (int i = 0; i < 32; ++i) bot[i] = fminf(bot[i], pb[31 - i]);
    clean32_asc(bot);
  }

  // --- cross-wave tree merge via LDS: 8 -> 4 -> 2 -> 1 ---
  __shared__ float lds[4 * 32 * 64];   // 32 KB

  #pragma unroll
  for (int half = 4; half >= 1; half >>= 1) {
    __syncthreads();
    if (w >= half && w < 2 * half && lane < 32) {
      float* dst = &lds[((w - half) * 32 + lane) * 64];
      #pragma unroll
      for (int i = 0; i < 32; ++i) { dst[i] = top[i]; dst[32 + i] = bot[i]; }
    }
    __syncthreads();
    if (w < half && lane < 32) {
      const float* src = &lds[(w * 32 + lane) * 64];
      float pt[32], pb[32];
      #pragma unroll
      for (int i = 0; i < 32; ++i) { pt[i] = src[i]; pb[i] = src[32 + i]; }
      #pragma unroll
      for (int i = 0; i < 32; ++i) top[i] = fmaxf(top[i], pt[31 - i]);
      clean32_desc(top);
      #pragma unroll
      for (int i = 0; i < 32; ++i) bot[i] = fminf(bot[i], pb[31 - i]);
      clean32_asc(bot);
    }
  }

  if (w == 0 && lane < 32) {
    float s = 0.f;
    #pragma unroll
    for (int i = 0; i < K; ++i) s += top[i] + bot[i];
    out[b * CH + cbase + lane] = s * (1.0f / K);
  }
}

extern "C" void kernel_launch(void* const* d_in, const int* in_sizes, int n_in,
                              void* d_out, int out_size, void* d_ws, size_t ws_size,
                              hipStream_t stream) {
  const float* x = (const float*)d_in[0];
  float* out = (float*)d_out;
  // grid: 32 (B) * 16 channel-groups = 512 blocks, 512 threads each
  hipLaunchKernelGGL(wildcat_topk_kernel, dim3(512), dim3(512), 0, stream, x, out);
}